// Round 7
// baseline (981.508 us; speedup 1.0000x reference)
//
#include <hip/hip_runtime.h>
#include <math.h>

#define N_NODES 10000
#define N_EDGES 80000
#define N_GRAPH 64
#define DD 64
#define HIDW 128
#define F_IN 14
#define EAD 4
#define KSMAX 8   // total K-split partial slots (HIDW*64/1024)

typedef _Float16 f16x8 __attribute__((ext_vector_type(8)));
typedef float f32x4 __attribute__((ext_vector_type(4)));

__device__ __forceinline__ float sigmoidf_(float x){ return 1.0f/(1.0f+expf(-x)); }

// monotone float<->uint key for atomicMax on floats
__device__ __forceinline__ unsigned fkey(float f){
  unsigned u = __float_as_uint(f);
  return u ^ ((((int)u) >> 31) | 0x80000000u);
}
__device__ __forceinline__ float funkey(unsigned k){
  unsigned u = (k & 0x80000000u) ? (k ^ 0x80000000u) : ~k;
  return __uint_as_float(u);
}

// ---------- prep kernels ----------

// Pack h2_w into fp16 MFMA B-fragment order:
// Bp[((st*4+cg)*64+lane)*8+j] = h2w[h, i*64+o], k=st*32+(lane>>4)*8+j, o=cg*16+(lane&15), h=k>>6, i=k&63
__global__ void k_prep_bpack(const float* __restrict__ h2w, _Float16* __restrict__ Bp){
  int idx = blockIdx.x*256 + threadIdx.x;
  if (idx >= (HIDW*DD/32)*4*64*8) return;
  int j = idx & 7, l = (idx >> 3) & 63, cg = (idx >> 9) & 3, st = idx >> 11;
  int k = st*32 + ((l >> 4) << 3) + j;
  int o = cg*16 + (l & 15);
  int h = k >> 6, i = k & 63;
  Bp[idx] = (_Float16)h2w[(size_t)h*4096 + i*64 + o];
}

// transpose GRU / LSTM weight matrices to k-major for coalesced reads
__global__ void k_prep_wT(const float* __restrict__ gih, const float* __restrict__ ghh,
                          const float* __restrict__ lih, const float* __restrict__ lhh,
                          float* __restrict__ WihT, float* __restrict__ WhhT,
                          float* __restrict__ IhT,  float* __restrict__ HhT){
  int idx = blockIdx.x*256 + threadIdx.x;
  if (idx < 12288){ int k=idx/192, j=idx%192; WihT[idx]=gih[j*64+k]; return; }
  idx -= 12288;
  if (idx < 12288){ int k=idx/192, j=idx%192; WhhT[idx]=ghh[j*64+k]; return; }
  idx -= 12288;
  if (idx < 32768){ int k=idx>>8, j=idx&255; IhT[idx]=lih[j*128+k]; return; }
  idx -= 32768;
  if (idx < 16384){ int k=idx>>8, j=idx&255; HhT[idx]=lhh[j*64+k]; return; }
}

// ---------- CSR build (sort edges by target) ----------

__global__ void k_count(const int* __restrict__ tgt, int* __restrict__ cnt){
  int e = blockIdx.x*256 + threadIdx.x;
  if (e < N_EDGES) atomicAdd(&cnt[tgt[e]], 1);
}

__global__ __launch_bounds__(1024) void k_scan(const int* __restrict__ cnt, int* __restrict__ offs,
                                               int* __restrict__ cursor, float* __restrict__ deg){
  __shared__ int sc[1024];
  int t = threadIdx.x;
  int base = t*10;
  int loc[10]; int tot = 0;
  #pragma unroll
  for (int j=0;j<10;++j){
    int i = base+j;
    int c = (i < N_NODES) ? cnt[i] : 0;
    loc[j] = tot; tot += c;
  }
  sc[t] = tot; __syncthreads();
  for (int st=1; st<1024; st<<=1){
    int v = (t>=st) ? sc[t-st] : 0;
    __syncthreads();
    sc[t] += v;
    __syncthreads();
  }
  int ex = sc[t] - tot;
  #pragma unroll
  for (int j=0;j<10;++j){
    int i = base+j;
    if (i < N_NODES){
      int o = ex + loc[j];
      offs[i] = o; cursor[i] = o;
      int c = cnt[i];
      deg[i] = (float)(c > 0 ? c : 1);
    }
  }
  if (t == 1023) offs[N_NODES] = sc[1023];
}

// sort edges by target; also pre-gather src in sorted order and record pos[e]
__global__ void k_sortE(const int* __restrict__ tgt, const int* __restrict__ src,
                        int* __restrict__ cursor, int* __restrict__ srcS, int* __restrict__ pos){
  int e = blockIdx.x*256 + threadIdx.x;
  if (e < N_EDGES){
    int p = atomicAdd(&cursor[tgt[e]], 1);
    srcS[p] = src[e];
    pos[e] = p;
  }
}

__global__ void k_graphoff(const int* __restrict__ batch, int* __restrict__ goff){
  int g = threadIdx.x;
  if (g > N_GRAPH) return;
  int lo = 0, hi = N_NODES;
  while (lo < hi){ int mid = (lo+hi)>>1; if (batch[mid] < g) lo = mid+1; else hi = mid; }
  goff[g] = lo;
}

// ---------- input layers ----------

__global__ __launch_bounds__(256) void k_lin0(const float* __restrict__ x, const float* __restrict__ w,
                                              const float* __restrict__ b, float* __restrict__ s){
  int tid = threadIdx.x;
  int g = tid >> 6, o = tid & 63;
  int n = blockIdx.x*4 + g;
  __shared__ float xL[4][F_IN];
  if (tid < 4*F_IN){
    int gg = tid / F_IN, k = tid % F_IN;
    int nn = blockIdx.x*4 + gg;
    xL[gg][k] = (nn < N_NODES) ? x[nn*F_IN + k] : 0.f;
  }
  __syncthreads();
  if (n >= N_NODES) return;
  float acc = b[o];
  #pragma unroll
  for (int k=0;k<F_IN;++k) acc += xL[g][k]*w[k*64+o];
  s[n*64+o] = fmaxf(acc, 0.f);
}

// hid = relu(ea@h1+b1), iteration-invariant; write in SORTED edge order (fp16)
__global__ __launch_bounds__(256) void k_hid(const float* __restrict__ ea,
    const float* __restrict__ h1_w, const float* __restrict__ h1_b,
    const int* __restrict__ pos, _Float16* __restrict__ hidS){
  int tid = threadIdx.x;
  int g = tid >> 7, j = tid & 127;
  int e = blockIdx.x*2 + g;
  __shared__ float eL[2][EAD];
  __shared__ int pL[2];
  if (tid < 8){ int gg = tid>>2, k = tid&3; eL[gg][k] = ea[(blockIdx.x*2+gg)*EAD + k]; }
  if (tid < 2) pL[tid] = pos[blockIdx.x*2 + tid];
  __syncthreads();
  (void)e;
  float v = h1_b[j];
  #pragma unroll
  for (int k=0;k<EAD;++k) v += eL[g][k]*h1_w[k*HIDW + j];
  hidS[(size_t)pL[g]*HIDW + j] = (_Float16)fmaxf(v, 0.f);
}

// ---------- per-iteration: P build (fp16 out) + MFMA GEMM ----------

template<int CH, bool WRITE_S>
__global__ __launch_bounds__(256) void k_aggpre_t(
    const float* __restrict__ s, const _Float16* __restrict__ hidS,
    const int* __restrict__ offs, const int* __restrict__ srcS, int c0,
    _Float16* __restrict__ P, float* __restrict__ Ssum){
  constexpr int RH = CH/4;
  int t = blockIdx.x;
  int tid = threadIdx.x;
  int i = tid & 63, hb = tid >> 6;
  __shared__ float sL[8][64];
  __shared__ float hidL[8][CH];
  float acc[RH];
  #pragma unroll
  for (int r=0;r<RH;++r) acc[r]=0.f;
  float sacc = 0.f;
  int e0 = offs[t], e1 = offs[t+1];
  for (int base = e0; base < e1; base += 8){
    int ecnt = min(8, e1 - base);
    __syncthreads();
    for (int a = tid; a < ecnt*64; a += 256){
      int j = a >> 6, ii = a & 63;
      sL[j][ii] = s[(size_t)srcS[base+j]*64 + ii];
    }
    for (int a = tid; a < ecnt*CH; a += 256){
      int j = a / CH, hh = a % CH;
      hidL[j][hh] = (float)hidS[(size_t)(base+j)*HIDW + c0 + hh];
    }
    __syncthreads();
    for (int j=0;j<ecnt;++j){
      float sv = sL[j][i];
      #pragma unroll
      for (int r=0;r<RH;++r) acc[r] += hidL[j][hb*RH + r]*sv;
      if (WRITE_S && hb==0) sacc += sv;
    }
  }
  _Float16* row = P + (size_t)t*(CH*64);
  #pragma unroll
  for (int r=0;r<RH;++r) row[(hb*RH + r)*64 + i] = (_Float16)acc[r];
  if (WRITE_S && hb==0) Ssum[(size_t)t*64 + i] = sacc;
}

// Cpart[y][10000][64] = A[10000,K] @ B[K,64] via LDS-staged mfma_f32_16x16x32_f16.
// Pure writes (slot pointer passed per chunk). 4 waves = 4 col-groups, 16 rows/block.
__global__ __launch_bounds__(256) void k_gemm_lds(const _Float16* __restrict__ A,
    const _Float16* __restrict__ Bp, float* __restrict__ Cpart, int K){
  __shared__ _Float16 tile[16*1024];
  int tid = threadIdx.x;
  int y = blockIdx.y;
  const size_t rowBytes = (size_t)K*2;
  {
    int sub = tid >> 7;
    int colb = (tid & 127) * 16;
    const char* Abase = (const char*)A + (size_t)(blockIdx.x*16)*rowBytes + (size_t)y*2048;
    #pragma unroll
    for (int i = 0; i < 8; ++i){
      int r = i*2 + sub;
      f16x8 v = *(const f16x8*)(Abase + (size_t)r*rowBytes + (size_t)(colb ^ ((r&7)<<4)));
      *(f16x8*)((char*)tile + r*2048 + colb) = v;
    }
  }
  __syncthreads();
  int cg = tid >> 6, lane = tid & 63;
  int row = lane & 15, kb = lane >> 4;
  const char* tbase = (const char*)tile + row*2048;
  int swz = (row & 7) << 4;
  f32x4 acc = 0.f;
  int fr0 = y*32*4;
  #pragma unroll 8
  for (int st = 0; st < 32; ++st){
    f16x8 af = *(const f16x8*)(tbase + ((st*64 + kb*16) ^ swz));
    f16x8 bf = *(const f16x8*)(Bp + ((size_t)(fr0 + st*4 + cg)*64 + lane)*8);
    acc = __builtin_amdgcn_mfma_f32_16x16x32_f16(af, bf, acc, 0, 0, 0);
  }
  int crow0 = blockIdx.x*16 + kb*4;
  int ccol = cg*16 + (lane & 15);
  float* base = Cpart + (size_t)y*(N_NODES*64);
  #pragma unroll
  for (int r=0;r<4;++r)
    base[(size_t)(crow0 + r)*64 + ccol] = acc[r];
}

// fused: 8-slot reduce, mean-deg, bias term (Ssum@h2b), conv-root, relu, GRU cell
__global__ __launch_bounds__(256) void k_node_update(const float* __restrict__ Cpart,
    const float* __restrict__ Ssum, const float* __restrict__ h2b,
    const float* __restrict__ deg, float* __restrict__ s,
    const float* __restrict__ conv_root, const float* __restrict__ conv_bias,
    const float* __restrict__ WihT, const float* __restrict__ WhhT,
    const float* __restrict__ bih, const float* __restrict__ bhh){
  int tid = threadIdx.x;
  int g = tid >> 6, o = tid & 63;
  int n = blockIdx.x*4 + g;
  __shared__ float hS[4][DD];
  __shared__ float mS[4][DD];
  __shared__ float ssS[4][DD];
  bool valid = n < N_NODES;
  float hold = valid ? s[(size_t)n*DD + o] : 0.f;
  hS[g][o] = hold;
  ssS[g][o] = valid ? Ssum[(size_t)n*DD + o] : 0.f;
  __syncthreads();
  float a = 0.f;
  if (valid){
    #pragma unroll
    for (int ks=0; ks<KSMAX; ++ks) a += Cpart[(size_t)ks*(N_NODES*64) + (size_t)n*64 + o];
  }
  #pragma unroll 8
  for (int k=0;k<DD;++k) a += ssS[g][k]*h2b[k*64+o];
  float dinv = valid ? 1.0f/deg[n] : 0.f;
  float acc = a*dinv + conv_bias[o];
  #pragma unroll 8
  for (int k=0;k<DD;++k) acc += hS[g][k]*conv_root[k*64+o];
  float m = fmaxf(acc, 0.f);
  mS[g][o] = m;
  __syncthreads();
  float gi0 = bih[o], gi1 = bih[64+o], gi2 = bih[128+o];
  float gh0 = bhh[o], gh1 = bhh[64+o], gh2 = bhh[128+o];
  for (int k=0;k<DD;++k){
    float mk = mS[g][k], hk = hS[g][k];
    gi0 += mk*WihT[k*192 + o];      gh0 += hk*WhhT[k*192 + o];
    gi1 += mk*WihT[k*192 + 64 + o]; gh1 += hk*WhhT[k*192 + 64 + o];
    gi2 += mk*WihT[k*192 + 128+ o]; gh2 += hk*WhhT[k*192 + 128+ o];
  }
  float r = sigmoidf_(gi0+gh0);
  float z = sigmoidf_(gi1+gh1);
  float nn = tanhf(gi2 + r*gh2);
  float hnew = (1.f - z)*nn + z*hold;
  if (valid) s[(size_t)n*DD + o] = hnew;
}

// ---------- Set2Set: node-parallel multi-kernel ----------

// per-graph LSTM cell; also re-init mkey/sum for this step
__global__ __launch_bounds__(256) void k_s2s_lstm(const float* __restrict__ qstar,
    float* __restrict__ hs, float* __restrict__ cs,
    const float* __restrict__ IhT, const float* __restrict__ HhT,
    const float* __restrict__ bih, const float* __restrict__ bhh,
    unsigned* __restrict__ mkey, float* __restrict__ sumb, int first){
  int g = blockIdx.x;
  int tid = threadIdx.x;
  __shared__ float qL[2*DD];
  __shared__ float hL[DD];
  __shared__ float gate[256];
  if (first){
    if (tid < 2*DD) qL[tid] = 0.f;
    if (tid < DD)   hL[tid] = 0.f;
  } else {
    if (tid < 2*DD) qL[tid] = qstar[g*2*DD + tid];
    if (tid < DD)   hL[tid] = hs[g*DD + tid];
  }
  __syncthreads();
  float acc = bih[tid] + bhh[tid];
  #pragma unroll 8
  for (int k=0;k<2*DD;++k) acc += qL[k]*IhT[k*256 + tid];
  #pragma unroll 8
  for (int k=0;k<DD;++k)   acc += hL[k]*HhT[k*256 + tid];
  gate[tid] = acc;
  __syncthreads();
  if (tid < DD){
    float i = sigmoidf_(gate[tid]);
    float f = sigmoidf_(gate[64+tid]);
    float gg = tanhf(gate[128+tid]);
    float o = sigmoidf_(gate[192+tid]);
    float cprev = first ? 0.f : cs[g*DD+tid];
    float c = f*cprev + i*gg;
    float h = o*tanhf(c);
    cs[g*DD+tid] = c;
    hs[g*DD+tid] = h;
  }
  if (tid == 64) mkey[g] = fkey(-3.0e38f);
  if (tid == 65) sumb[g] = 0.f;
}

// per-node dot e = out[n].q[batch[n]]; store e; atomicMax per-graph key
__global__ __launch_bounds__(256) void k_s2s_e(const float* __restrict__ sND,
    const float* __restrict__ hs, const int* __restrict__ batch,
    float* __restrict__ ebuf, unsigned* __restrict__ mkey){
  int w = threadIdx.x >> 6, lane = threadIdx.x & 63;
  int n = blockIdx.x*4 + w;
  int g = batch[n];
  float p = sND[(size_t)n*DD + lane] * hs[g*DD + lane];
  #pragma unroll
  for (int s2=32; s2>0; s2>>=1) p += __shfl_xor(p, s2, 64);
  if (lane == 0){
    ebuf[n] = p;
    atomicMax(&mkey[g], fkey(p));
  }
}

// per-node exp; wave-aggregated atomicAdd of the per-graph sum
__global__ __launch_bounds__(256) void k_s2s_x(float* __restrict__ ebuf,
    const int* __restrict__ batch, const unsigned* __restrict__ mkey,
    float* __restrict__ sumb){
  int n = blockIdx.x*256 + threadIdx.x;
  int lane = threadIdx.x & 63;
  float ex = 0.f; int g = -1;
  if (n < N_NODES){
    g = batch[n];
    float m = funkey(mkey[g]);
    ex = expf(ebuf[n] - m);
    ebuf[n] = ex;
  }
  int g0 = __shfl(g, 0, 64);
  bool uni = __all(g == g0);
  if (uni && g0 >= 0){
    float t = ex;
    #pragma unroll
    for (int s2=32; s2>0; s2>>=1) t += __shfl_xor(t, s2, 64);
    if (lane == 0) atomicAdd(&sumb[g0], t);
  } else if (n < N_NODES){
    atomicAdd(&sumb[g], ex);
  }
}

// per-graph weighted node sum; assemble qstar = [hs, r]
__global__ __launch_bounds__(256) void k_s2s_r(const float* __restrict__ sND,
    const float* __restrict__ ebuf, const int* __restrict__ goff,
    const float* __restrict__ hs, const float* __restrict__ sumb,
    float* __restrict__ qstar){
  int g = blockIdx.x;
  int tid = threadIdx.x;
  int d = tid & 63, w = tid >> 6;
  __shared__ float red2[4][DD];
  int n0 = goff[g], n1 = goff[g+1];
  float racc = 0.f;
  for (int n = n0 + w; n < n1; n += 4)
    racc += ebuf[n] * sND[(size_t)n*DD + d];
  red2[w][d] = racc;
  __syncthreads();
  if (tid < DD){
    float rs = red2[0][d]+red2[1][d]+red2[2][d]+red2[3][d];
    float st = sumb[g];
    qstar[g*2*DD + d]      = hs[g*DD + d];
    qstar[g*2*DD + DD + d] = (st > 0.f) ? rs/st : 0.f;
  }
}

__global__ __launch_bounds__(256) void k_final(const float* __restrict__ qstar,
    const float* __restrict__ lin1_w, const float* __restrict__ lin1_b,
    const float* __restrict__ lin2_w, const float* __restrict__ lin2_b,
    float* __restrict__ out){
  __shared__ float red[256];
  int tid = threadIdx.x;
  int g = tid >> 2, part = tid & 3;
  float acc = 0.f;
  for (int d = part*16; d < part*16+16; ++d){
    float z = lin1_b[d];
    #pragma unroll 8
    for (int k=0;k<2*DD;++k) z += qstar[g*2*DD+k]*lin1_w[k*64+d];
    z = fmaxf(z, 0.f);
    acc += z * lin2_w[d];
  }
  red[tid] = acc;
  __syncthreads();
  if (part == 0) out[g] = red[tid]+red[tid+1]+red[tid+2]+red[tid+3] + lin2_b[0];
}

// ---------- launch ----------

static inline size_t alignup(size_t x){ return (x + 255) & ~(size_t)255; }

extern "C" void kernel_launch(void* const* d_in, const int* in_sizes, int n_in,
                              void* d_out, int out_size, void* d_ws, size_t ws_size,
                              hipStream_t stream){
  const float* x      = (const float*)d_in[0];
  const int*   ei     = (const int*)  d_in[1];
  const float* ea     = (const float*)d_in[2];
  const int*   batch  = (const int*)  d_in[3];
  const float* lin0_w = (const float*)d_in[5];
  const float* lin0_b = (const float*)d_in[6];
  const float* h1_w   = (const float*)d_in[7];
  const float* h1_b   = (const float*)d_in[8];
  const float* h2_w   = (const float*)d_in[9];
  const float* h2_b   = (const float*)d_in[10];
  const float* conv_root = (const float*)d_in[11];
  const float* conv_bias = (const float*)d_in[12];
  const float* gru_w_ih  = (const float*)d_in[13];
  const float* gru_w_hh  = (const float*)d_in[14];
  const float* gru_b_ih  = (const float*)d_in[15];
  const float* gru_b_hh  = (const float*)d_in[16];
  const float* lstm_w_ih = (const float*)d_in[17];
  const float* lstm_w_hh = (const float*)d_in[18];
  const float* lstm_b_ih = (const float*)d_in[19];
  const float* lstm_b_hh = (const float*)d_in[20];
  const float* lin1_w = (const float*)d_in[21];
  const float* lin1_b = (const float*)d_in[22];
  const float* lin2_w = (const float*)d_in[23];
  const float* lin2_b = (const float*)d_in[24];
  (void)in_sizes; (void)n_in; (void)out_size;

  const int* srcA = ei;
  const int* tgtA = ei + N_EDGES;

  // ---- fixed workspace layout (~49 MB) ----
  char* p = (char*)d_ws;
  size_t off = 0;
  auto take = [&](size_t bytes)->char*{ char* q = p + off; off = alignup(off + bytes); return q; };
  _Float16* Bpack = (_Float16*)take((size_t)(HIDW*DD/32)*4*64*8*2);   // 1.05 MB
  float* sbuf     = (float*)take((size_t)N_NODES*DD*4);
  float* Cpart    = (float*)take((size_t)KSMAX*N_NODES*DD*4);         // 20.48 MB
  float* Ssum     = (float*)take((size_t)N_NODES*DD*4);
  _Float16* hidS  = (_Float16*)take((size_t)N_EDGES*HIDW*2);          // 20.48 MB
  float* WihT    = (float*)take(12288*4);
  float* WhhT    = (float*)take(12288*4);
  float* IhT     = (float*)take(32768*4);
  float* HhT     = (float*)take(16384*4);
  float* deg     = (float*)take(N_NODES*4);
  int*   cnt     = (int*)  take(N_NODES*4);
  int*   offs    = (int*)  take((N_NODES+1)*4);
  int*   cursor  = (int*)  take(N_NODES*4);
  int*   srcS    = (int*)  take(N_EDGES*4);
  int*   pos     = (int*)  take(N_EDGES*4);
  int*   goff    = (int*)  take(65*4);
  float* qstar   = (float*)take((size_t)N_GRAPH*2*DD*4);
  float* hsb     = (float*)take((size_t)N_GRAPH*DD*4);
  float* csb     = (float*)take((size_t)N_GRAPH*DD*4);
  unsigned* mkey = (unsigned*)take(N_GRAPH*4);
  float* sumb    = (float*)take(N_GRAPH*4);
  float* ebuf    = (float*)take(N_NODES*4);
  size_t fixed_bytes = off;

  // ---- adaptive P-chunk selection (fp16); K per chunk = CH*64 >= 1024 ----
  int CH = 16;
  const int cands[4] = {128, 64, 32, 16};
  for (int ci = 0; ci < 4; ++ci){
    size_t need = fixed_bytes + (size_t)N_NODES * cands[ci] * 64 * 2;
    if (need <= ws_size){ CH = cands[ci]; break; }
  }
  _Float16* Pbuf = (_Float16*)take((size_t)N_NODES*CH*64*2);
  const int K = CH*64;
  const int nslots = K / 1024;   // Cpart slots per chunk (>=1); total across chunks = 8

  hipMemsetAsync(cnt, 0, N_NODES*4, stream);

  k_prep_bpack<<<(HIDW*DD/32)*4*64*8/256, 256, 0, stream>>>(h2_w, Bpack);
  k_prep_wT<<<(12288*2+32768+16384)/256, 256, 0, stream>>>(gru_w_ih, gru_w_hh, lstm_w_ih, lstm_w_hh,
                                                           WihT, WhhT, IhT, HhT);
  k_count<<<(N_EDGES+255)/256, 256, 0, stream>>>(tgtA, cnt);
  k_scan<<<1, 1024, 0, stream>>>(cnt, offs, cursor, deg);
  k_sortE<<<(N_EDGES+255)/256, 256, 0, stream>>>(tgtA, srcA, cursor, srcS, pos);
  k_graphoff<<<1, 128, 0, stream>>>(batch, goff);
  k_lin0<<<N_NODES/4, 256, 0, stream>>>(x, lin0_w, lin0_b, sbuf);
  k_hid<<<N_EDGES/2, 256, 0, stream>>>(ea, h1_w, h1_b, pos, hidS);

  auto launch_agg = [&](int c0, bool writeS){
    dim3 g(N_NODES);
    if (writeS){
      switch (CH){
        case 128: k_aggpre_t<128,true><<<g,256,0,stream>>>(sbuf,hidS,offs,srcS,c0,Pbuf,Ssum); break;
        case  64: k_aggpre_t< 64,true><<<g,256,0,stream>>>(sbuf,hidS,offs,srcS,c0,Pbuf,Ssum); break;
        case  32: k_aggpre_t< 32,true><<<g,256,0,stream>>>(sbuf,hidS,offs,srcS,c0,Pbuf,Ssum); break;
        default : k_aggpre_t< 16,true><<<g,256,0,stream>>>(sbuf,hidS,offs,srcS,c0,Pbuf,Ssum); break;
      }
    } else {
      switch (CH){
        case 128: k_aggpre_t<128,false><<<g,256,0,stream>>>(sbuf,hidS,offs,srcS,c0,Pbuf,Ssum); break;
        case  64: k_aggpre_t< 64,false><<<g,256,0,stream>>>(sbuf,hidS,offs,srcS,c0,Pbuf,Ssum); break;
        case  32: k_aggpre_t< 32,false><<<g,256,0,stream>>>(sbuf,hidS,offs,srcS,c0,Pbuf,Ssum); break;
        default : k_aggpre_t< 16,false><<<g,256,0,stream>>>(sbuf,hidS,offs,srcS,c0,Pbuf,Ssum); break;
      }
    }
  };

  for (int it = 0; it < 3; ++it){
    int nch = HIDW / CH;
    for (int c = 0; c < nch; ++c){
      int c0 = c*CH;
      launch_agg(c0, c == 0);
      k_gemm_lds<<<dim3(N_NODES/16, nslots), 256, 0, stream>>>(
          Pbuf, Bpack + (size_t)(c0*2)*(4*64*8),
          Cpart + (size_t)(c*nslots)*(N_NODES*64), K);
    }
    k_node_update<<<N_NODES/4, 256, 0, stream>>>(Cpart, Ssum, h2_b, deg, sbuf, conv_root, conv_bias,
                                                 WihT, WhhT, gru_b_ih, gru_b_hh);
  }

  for (int st = 0; st < 3; ++st){
    k_s2s_lstm<<<N_GRAPH, 256, 0, stream>>>(qstar, hsb, csb, IhT, HhT, lstm_b_ih, lstm_b_hh,
                                            mkey, sumb, st == 0);
    k_s2s_e<<<N_NODES/4, 256, 0, stream>>>(sbuf, hsb, batch, ebuf, mkey);
    k_s2s_x<<<(N_NODES+255)/256, 256, 0, stream>>>(ebuf, batch, mkey, sumb);
    k_s2s_r<<<N_GRAPH, 256, 0, stream>>>(sbuf, ebuf, goff, hsb, sumb, qstar);
  }
  k_final<<<1, 256, 0, stream>>>(qstar, lin1_w, lin1_b, lin2_w, lin2_b, (float*)d_out);
}

// Round 8
// 666.087 us; speedup vs baseline: 1.4735x; 1.4735x over previous
//
#include <hip/hip_runtime.h>
#include <math.h>

#define N_NODES 10000
#define N_EDGES 80000
#define N_GRAPH 64
#define DD 64
#define HIDW 128
#define F_IN 14
#define EAD 4
#define KSMAX 8   // total K-split partial slots (HIDW*64/1024)

typedef _Float16 f16x8 __attribute__((ext_vector_type(8)));
typedef float f32x4 __attribute__((ext_vector_type(4)));

__device__ __forceinline__ float sigmoidf_(float x){ return 1.0f/(1.0f+expf(-x)); }

// ---------- prep kernels ----------

// Pack h2_w into fp16 MFMA B-fragment order:
// Bp[((st*4+cg)*64+lane)*8+j] = h2w[h, i*64+o], k=st*32+(lane>>4)*8+j, o=cg*16+(lane&15), h=k>>6, i=k&63
__global__ void k_prep_bpack(const float* __restrict__ h2w, _Float16* __restrict__ Bp){
  int idx = blockIdx.x*256 + threadIdx.x;
  if (idx >= (HIDW*DD/32)*4*64*8) return;
  int j = idx & 7, l = (idx >> 3) & 63, cg = (idx >> 9) & 3, st = idx >> 11;
  int k = st*32 + ((l >> 4) << 3) + j;
  int o = cg*16 + (l & 15);
  int h = k >> 6, i = k & 63;
  Bp[idx] = (_Float16)h2w[(size_t)h*4096 + i*64 + o];
}

// transpose GRU / LSTM weight matrices to k-major for coalesced reads
__global__ void k_prep_wT(const float* __restrict__ gih, const float* __restrict__ ghh,
                          const float* __restrict__ lih, const float* __restrict__ lhh,
                          float* __restrict__ WihT, float* __restrict__ WhhT,
                          float* __restrict__ IhT,  float* __restrict__ HhT){
  int idx = blockIdx.x*256 + threadIdx.x;
  if (idx < 12288){ int k=idx/192, j=idx%192; WihT[idx]=gih[j*64+k]; return; }
  idx -= 12288;
  if (idx < 12288){ int k=idx/192, j=idx%192; WhhT[idx]=ghh[j*64+k]; return; }
  idx -= 12288;
  if (idx < 32768){ int k=idx>>8, j=idx&255; IhT[idx]=lih[j*128+k]; return; }
  idx -= 32768;
  if (idx < 16384){ int k=idx>>8, j=idx&255; HhT[idx]=lhh[j*64+k]; return; }
}

// ---------- CSR build (sort edges by target) ----------

__global__ void k_count(const int* __restrict__ tgt, int* __restrict__ cnt){
  int e = blockIdx.x*256 + threadIdx.x;
  if (e < N_EDGES) atomicAdd(&cnt[tgt[e]], 1);
}

__global__ __launch_bounds__(1024) void k_scan(const int* __restrict__ cnt, int* __restrict__ offs,
                                               int* __restrict__ cursor, float* __restrict__ deg){
  __shared__ int sc[1024];
  int t = threadIdx.x;
  int base = t*10;
  int loc[10]; int tot = 0;
  #pragma unroll
  for (int j=0;j<10;++j){
    int i = base+j;
    int c = (i < N_NODES) ? cnt[i] : 0;
    loc[j] = tot; tot += c;
  }
  sc[t] = tot; __syncthreads();
  for (int st=1; st<1024; st<<=1){
    int v = (t>=st) ? sc[t-st] : 0;
    __syncthreads();
    sc[t] += v;
    __syncthreads();
  }
  int ex = sc[t] - tot;
  #pragma unroll
  for (int j=0;j<10;++j){
    int i = base+j;
    if (i < N_NODES){
      int o = ex + loc[j];
      offs[i] = o; cursor[i] = o;
      int c = cnt[i];
      deg[i] = (float)(c > 0 ? c : 1);
    }
  }
  if (t == 1023) offs[N_NODES] = sc[1023];
}

// sort edges by target; also pre-gather src in sorted order and record pos[e]
__global__ void k_sortE(const int* __restrict__ tgt, const int* __restrict__ src,
                        int* __restrict__ cursor, int* __restrict__ srcS, int* __restrict__ pos){
  int e = blockIdx.x*256 + threadIdx.x;
  if (e < N_EDGES){
    int p = atomicAdd(&cursor[tgt[e]], 1);
    srcS[p] = src[e];
    pos[e] = p;
  }
}

__global__ void k_graphoff(const int* __restrict__ batch, int* __restrict__ goff){
  int g = threadIdx.x;
  if (g > N_GRAPH) return;
  int lo = 0, hi = N_NODES;
  while (lo < hi){ int mid = (lo+hi)>>1; if (batch[mid] < g) lo = mid+1; else hi = mid; }
  goff[g] = lo;
}

// ---------- input layers ----------

__global__ __launch_bounds__(256) void k_lin0(const float* __restrict__ x, const float* __restrict__ w,
                                              const float* __restrict__ b, float* __restrict__ s){
  int tid = threadIdx.x;
  int g = tid >> 6, o = tid & 63;
  int n = blockIdx.x*4 + g;
  __shared__ float xL[4][F_IN];
  if (tid < 4*F_IN){
    int gg = tid / F_IN, k = tid % F_IN;
    int nn = blockIdx.x*4 + gg;
    xL[gg][k] = (nn < N_NODES) ? x[nn*F_IN + k] : 0.f;
  }
  __syncthreads();
  if (n >= N_NODES) return;
  float acc = b[o];
  #pragma unroll
  for (int k=0;k<F_IN;++k) acc += xL[g][k]*w[k*64+o];
  s[n*64+o] = fmaxf(acc, 0.f);
}

// hid = relu(ea@h1+b1), iteration-invariant; write in SORTED edge order (fp16)
__global__ __launch_bounds__(256) void k_hid(const float* __restrict__ ea,
    const float* __restrict__ h1_w, const float* __restrict__ h1_b,
    const int* __restrict__ pos, _Float16* __restrict__ hidS){
  int tid = threadIdx.x;
  int g = tid >> 7, j = tid & 127;
  __shared__ float eL[2][EAD];
  __shared__ int pL[2];
  if (tid < 8){ int gg = tid>>2, k = tid&3; eL[gg][k] = ea[(blockIdx.x*2+gg)*EAD + k]; }
  if (tid < 2) pL[tid] = pos[blockIdx.x*2 + tid];
  __syncthreads();
  float v = h1_b[j];
  #pragma unroll
  for (int k=0;k<EAD;++k) v += eL[g][k]*h1_w[k*HIDW + j];
  hidS[(size_t)pL[g]*HIDW + j] = (_Float16)fmaxf(v, 0.f);
}

// ---------- per-iteration: P build (fp16 out) + MFMA GEMM ----------

template<int CH, bool WRITE_S>
__global__ __launch_bounds__(256) void k_aggpre_t(
    const float* __restrict__ s, const _Float16* __restrict__ hidS,
    const int* __restrict__ offs, const int* __restrict__ srcS, int c0,
    _Float16* __restrict__ P, float* __restrict__ Ssum){
  constexpr int RH = CH/4;
  int t = blockIdx.x;
  int tid = threadIdx.x;
  int i = tid & 63, hb = tid >> 6;
  __shared__ float sL[8][64];
  __shared__ float hidL[8][CH];
  float acc[RH];
  #pragma unroll
  for (int r=0;r<RH;++r) acc[r]=0.f;
  float sacc = 0.f;
  int e0 = offs[t], e1 = offs[t+1];
  for (int base = e0; base < e1; base += 8){
    int ecnt = min(8, e1 - base);
    __syncthreads();
    for (int a = tid; a < ecnt*64; a += 256){
      int j = a >> 6, ii = a & 63;
      sL[j][ii] = s[(size_t)srcS[base+j]*64 + ii];
    }
    for (int a = tid; a < ecnt*CH; a += 256){
      int j = a / CH, hh = a % CH;
      hidL[j][hh] = (float)hidS[(size_t)(base+j)*HIDW + c0 + hh];
    }
    __syncthreads();
    for (int j=0;j<ecnt;++j){
      float sv = sL[j][i];
      #pragma unroll
      for (int r=0;r<RH;++r) acc[r] += hidL[j][hb*RH + r]*sv;
      if (WRITE_S && hb==0) sacc += sv;
    }
  }
  _Float16* row = P + (size_t)t*(CH*64);
  #pragma unroll
  for (int r=0;r<RH;++r) row[(hb*RH + r)*64 + i] = (_Float16)acc[r];
  if (WRITE_S && hb==0) Ssum[(size_t)t*64 + i] = sacc;
}

// Cpart[y][10000][64] = A[10000,K] @ B[K,64] via LDS-staged mfma_f32_16x16x32_f16.
__global__ __launch_bounds__(256) void k_gemm_lds(const _Float16* __restrict__ A,
    const _Float16* __restrict__ Bp, float* __restrict__ Cpart, int K){
  __shared__ _Float16 tile[16*1024];
  int tid = threadIdx.x;
  int y = blockIdx.y;
  const size_t rowBytes = (size_t)K*2;
  {
    int sub = tid >> 7;
    int colb = (tid & 127) * 16;
    const char* Abase = (const char*)A + (size_t)(blockIdx.x*16)*rowBytes + (size_t)y*2048;
    #pragma unroll
    for (int i = 0; i < 8; ++i){
      int r = i*2 + sub;
      f16x8 v = *(const f16x8*)(Abase + (size_t)r*rowBytes + (size_t)(colb ^ ((r&7)<<4)));
      *(f16x8*)((char*)tile + r*2048 + colb) = v;
    }
  }
  __syncthreads();
  int cg = tid >> 6, lane = tid & 63;
  int row = lane & 15, kb = lane >> 4;
  const char* tbase = (const char*)tile + row*2048;
  int swz = (row & 7) << 4;
  f32x4 acc = 0.f;
  int fr0 = y*32*4;
  #pragma unroll 8
  for (int st = 0; st < 32; ++st){
    f16x8 af = *(const f16x8*)(tbase + ((st*64 + kb*16) ^ swz));
    f16x8 bf = *(const f16x8*)(Bp + ((size_t)(fr0 + st*4 + cg)*64 + lane)*8);
    acc = __builtin_amdgcn_mfma_f32_16x16x32_f16(af, bf, acc, 0, 0, 0);
  }
  int crow0 = blockIdx.x*16 + kb*4;
  int ccol = cg*16 + (lane & 15);
  float* base = Cpart + (size_t)y*(N_NODES*64);
  #pragma unroll
  for (int r=0;r<4;++r)
    base[(size_t)(crow0 + r)*64 + ccol] = acc[r];
}

// fused: 8-slot reduce, mean-deg, bias term (Ssum@h2b), conv-root, relu, GRU cell
__global__ __launch_bounds__(256) void k_node_update(const float* __restrict__ Cpart,
    const float* __restrict__ Ssum, const float* __restrict__ h2b,
    const float* __restrict__ deg, float* __restrict__ s,
    const float* __restrict__ conv_root, const float* __restrict__ conv_bias,
    const float* __restrict__ WihT, const float* __restrict__ WhhT,
    const float* __restrict__ bih, const float* __restrict__ bhh){
  int tid = threadIdx.x;
  int g = tid >> 6, o = tid & 63;
  int n = blockIdx.x*4 + g;
  __shared__ float hS[4][DD];
  __shared__ float mS[4][DD];
  __shared__ float ssS[4][DD];
  bool valid = n < N_NODES;
  float hold = valid ? s[(size_t)n*DD + o] : 0.f;
  hS[g][o] = hold;
  ssS[g][o] = valid ? Ssum[(size_t)n*DD + o] : 0.f;
  __syncthreads();
  float a = 0.f;
  if (valid){
    #pragma unroll
    for (int ks=0; ks<KSMAX; ++ks) a += Cpart[(size_t)ks*(N_NODES*64) + (size_t)n*64 + o];
  }
  #pragma unroll 8
  for (int k=0;k<DD;++k) a += ssS[g][k]*h2b[k*64+o];
  float dinv = valid ? 1.0f/deg[n] : 0.f;
  float acc = a*dinv + conv_bias[o];
  #pragma unroll 8
  for (int k=0;k<DD;++k) acc += hS[g][k]*conv_root[k*64+o];
  float m = fmaxf(acc, 0.f);
  mS[g][o] = m;
  __syncthreads();
  float gi0 = bih[o], gi1 = bih[64+o], gi2 = bih[128+o];
  float gh0 = bhh[o], gh1 = bhh[64+o], gh2 = bhh[128+o];
  for (int k=0;k<DD;++k){
    float mk = mS[g][k], hk = hS[g][k];
    gi0 += mk*WihT[k*192 + o];      gh0 += hk*WhhT[k*192 + o];
    gi1 += mk*WihT[k*192 + 64 + o]; gh1 += hk*WhhT[k*192 + 64 + o];
    gi2 += mk*WihT[k*192 + 128+ o]; gh2 += hk*WhhT[k*192 + 128+ o];
  }
  float r = sigmoidf_(gi0+gh0);
  float z = sigmoidf_(gi1+gh1);
  float nn = tanhf(gi2 + r*gh2);
  float hnew = (1.f - z)*nn + z*hold;
  if (valid) s[(size_t)n*DD + o] = hnew;
}

// ---------- Set2Set: node-parallel, deterministic (no global atomics) ----------

// per-graph LSTM cell
__global__ __launch_bounds__(256) void k_s2s_lstm(const float* __restrict__ qstar,
    float* __restrict__ hs, float* __restrict__ cs,
    const float* __restrict__ IhT, const float* __restrict__ HhT,
    const float* __restrict__ bih, const float* __restrict__ bhh, int first){
  int g = blockIdx.x;
  int tid = threadIdx.x;
  __shared__ float qL[2*DD];
  __shared__ float hL[DD];
  __shared__ float gate[256];
  if (first){
    if (tid < 2*DD) qL[tid] = 0.f;
    if (tid < DD)   hL[tid] = 0.f;
  } else {
    if (tid < 2*DD) qL[tid] = qstar[g*2*DD + tid];
    if (tid < DD)   hL[tid] = hs[g*DD + tid];
  }
  __syncthreads();
  float acc = bih[tid] + bhh[tid];
  #pragma unroll 8
  for (int k=0;k<2*DD;++k) acc += qL[k]*IhT[k*256 + tid];
  #pragma unroll 8
  for (int k=0;k<DD;++k)   acc += hL[k]*HhT[k*256 + tid];
  gate[tid] = acc;
  __syncthreads();
  if (tid < DD){
    float i = sigmoidf_(gate[tid]);
    float f = sigmoidf_(gate[64+tid]);
    float gg = tanhf(gate[128+tid]);
    float o = sigmoidf_(gate[192+tid]);
    float cprev = first ? 0.f : cs[g*DD+tid];
    float c = f*cprev + i*gg;
    float h = o*tanhf(c);
    cs[g*DD+tid] = c;
    hs[g*DD+tid] = h;
  }
}

// per-node dot e = out[n].q[batch[n]] (plain store, no atomics)
__global__ __launch_bounds__(256) void k_s2s_e(const float* __restrict__ sND,
    const float* __restrict__ hs, const int* __restrict__ batch,
    float* __restrict__ ebuf){
  int w = threadIdx.x >> 6, lane = threadIdx.x & 63;
  int n = blockIdx.x*4 + w;
  int g = batch[n];
  float p = sND[(size_t)n*DD + lane] * hs[g*DD + lane];
  #pragma unroll
  for (int s2=32; s2>0; s2>>=1) p += __shfl_xor(p, s2, 64);
  if (lane == 0) ebuf[n] = p;
}

// per-graph segmented softmax: max + exp-in-place + inv-sum (deterministic LDS tree)
__global__ __launch_bounds__(256) void k_s2s_ms(float* __restrict__ ebuf,
    const int* __restrict__ goff, float* __restrict__ sinv){
  int g = blockIdx.x, tid = threadIdx.x;
  __shared__ float red[256];
  int n0 = goff[g], n1 = goff[g+1];
  float m = -INFINITY;
  for (int n = n0 + tid; n < n1; n += 256) m = fmaxf(m, ebuf[n]);
  red[tid] = m; __syncthreads();
  for (int s = 128; s > 0; s >>= 1){
    if (tid < s) red[tid] = fmaxf(red[tid], red[tid+s]);
    __syncthreads();
  }
  m = red[0]; __syncthreads();
  float sum = 0.f;
  for (int n = n0 + tid; n < n1; n += 256){
    float ex = expf(ebuf[n] - m);
    ebuf[n] = ex;
    sum += ex;
  }
  red[tid] = sum; __syncthreads();
  for (int s = 128; s > 0; s >>= 1){
    if (tid < s) red[tid] += red[tid+s];
    __syncthreads();
  }
  if (tid == 0) sinv[g] = (red[0] > 0.f) ? 1.0f/red[0] : 0.f;
}

// slice-partial weighted node sums: rpart[g][slice][d]
__global__ __launch_bounds__(256) void k_s2s_rp(const float* __restrict__ sND,
    const float* __restrict__ ebuf, const int* __restrict__ goff,
    float* __restrict__ rpart){
  int g = blockIdx.x, slice = blockIdx.y;
  int w = threadIdx.x >> 6, lane = threadIdx.x & 63;
  __shared__ float red2[4][64];
  int n0 = goff[g], n1 = goff[g+1];
  float acc = 0.f;
  for (int n = n0 + slice*4 + w; n < n1; n += 32)
    acc += ebuf[n] * sND[(size_t)n*DD + lane];
  red2[w][lane] = acc; __syncthreads();
  if (w == 0)
    rpart[((size_t)g*8 + slice)*64 + lane] = red2[0][lane]+red2[1][lane]+red2[2][lane]+red2[3][lane];
}

// fold slices, scale by sinv, assemble qstar = [hs, r]
__global__ __launch_bounds__(64) void k_s2s_rf(const float* __restrict__ rpart,
    const float* __restrict__ hs, const float* __restrict__ sinv,
    float* __restrict__ qstar){
  int g = blockIdx.x, d = threadIdx.x;
  float r = 0.f;
  #pragma unroll
  for (int s = 0; s < 8; ++s) r += rpart[((size_t)g*8 + s)*64 + d];
  qstar[g*2*DD + d]      = hs[g*DD + d];
  qstar[g*2*DD + DD + d] = r * sinv[g];
}

// final MLP: one block per graph
__global__ __launch_bounds__(256) void k_final64(const float* __restrict__ qstar,
    const float* __restrict__ lin1_w, const float* __restrict__ lin1_b,
    const float* __restrict__ lin2_w, const float* __restrict__ lin2_b,
    float* __restrict__ out){
  int g = blockIdx.x, tid = threadIdx.x;
  int d = tid & 63, part = tid >> 6;
  __shared__ float qL[2*DD];
  __shared__ float red[4][64];
  if (tid < 2*DD) qL[tid] = qstar[g*2*DD + tid];
  __syncthreads();
  float acc = 0.f;
  for (int k = part*32; k < part*32 + 32; ++k) acc += qL[k]*lin1_w[k*64 + d];
  red[part][d] = acc; __syncthreads();
  if (tid < 64){
    float z = fmaxf(lin1_b[d] + red[0][d]+red[1][d]+red[2][d]+red[3][d], 0.f);
    float p = z * lin2_w[d];
    #pragma unroll
    for (int s2=32; s2>0; s2>>=1) p += __shfl_xor(p, s2, 64);
    if (d == 0) out[g] = p + lin2_b[0];
  }
}

// ---------- launch ----------

static inline size_t alignup(size_t x){ return (x + 255) & ~(size_t)255; }

extern "C" void kernel_launch(void* const* d_in, const int* in_sizes, int n_in,
                              void* d_out, int out_size, void* d_ws, size_t ws_size,
                              hipStream_t stream){
  const float* x      = (const float*)d_in[0];
  const int*   ei     = (const int*)  d_in[1];
  const float* ea     = (const float*)d_in[2];
  const int*   batch  = (const int*)  d_in[3];
  const float* lin0_w = (const float*)d_in[5];
  const float* lin0_b = (const float*)d_in[6];
  const float* h1_w   = (const float*)d_in[7];
  const float* h1_b   = (const float*)d_in[8];
  const float* h2_w   = (const float*)d_in[9];
  const float* h2_b   = (const float*)d_in[10];
  const float* conv_root = (const float*)d_in[11];
  const float* conv_bias = (const float*)d_in[12];
  const float* gru_w_ih  = (const float*)d_in[13];
  const float* gru_w_hh  = (const float*)d_in[14];
  const float* gru_b_ih  = (const float*)d_in[15];
  const float* gru_b_hh  = (const float*)d_in[16];
  const float* lstm_w_ih = (const float*)d_in[17];
  const float* lstm_w_hh = (const float*)d_in[18];
  const float* lstm_b_ih = (const float*)d_in[19];
  const float* lstm_b_hh = (const float*)d_in[20];
  const float* lin1_w = (const float*)d_in[21];
  const float* lin1_b = (const float*)d_in[22];
  const float* lin2_w = (const float*)d_in[23];
  const float* lin2_b = (const float*)d_in[24];
  (void)in_sizes; (void)n_in; (void)out_size;

  const int* srcA = ei;
  const int* tgtA = ei + N_EDGES;

  // ---- fixed workspace layout (~49 MB) ----
  char* p = (char*)d_ws;
  size_t off = 0;
  auto take = [&](size_t bytes)->char*{ char* q = p + off; off = alignup(off + bytes); return q; };
  _Float16* Bpack = (_Float16*)take((size_t)(HIDW*DD/32)*4*64*8*2);   // 1.05 MB
  float* sbuf     = (float*)take((size_t)N_NODES*DD*4);
  float* Cpart    = (float*)take((size_t)KSMAX*N_NODES*DD*4);         // 20.48 MB
  float* Ssum     = (float*)take((size_t)N_NODES*DD*4);
  _Float16* hidS  = (_Float16*)take((size_t)N_EDGES*HIDW*2);          // 20.48 MB
  float* WihT    = (float*)take(12288*4);
  float* WhhT    = (float*)take(12288*4);
  float* IhT     = (float*)take(32768*4);
  float* HhT     = (float*)take(16384*4);
  float* deg     = (float*)take(N_NODES*4);
  int*   cnt     = (int*)  take(N_NODES*4);
  int*   offs    = (int*)  take((N_NODES+1)*4);
  int*   cursor  = (int*)  take(N_NODES*4);
  int*   srcS    = (int*)  take(N_EDGES*4);
  int*   pos     = (int*)  take(N_EDGES*4);
  int*   goff    = (int*)  take(65*4);
  float* qstar   = (float*)take((size_t)N_GRAPH*2*DD*4);
  float* hsb     = (float*)take((size_t)N_GRAPH*DD*4);
  float* csb     = (float*)take((size_t)N_GRAPH*DD*4);
  float* sinv    = (float*)take(N_GRAPH*4);
  float* rpart   = (float*)take((size_t)N_GRAPH*8*DD*4);
  float* ebuf    = (float*)take(N_NODES*4);
  size_t fixed_bytes = off;

  // ---- adaptive P-chunk selection (fp16); K per chunk = CH*64 >= 1024 ----
  int CH = 16;
  const int cands[4] = {128, 64, 32, 16};
  for (int ci = 0; ci < 4; ++ci){
    size_t need = fixed_bytes + (size_t)N_NODES * cands[ci] * 64 * 2;
    if (need <= ws_size){ CH = cands[ci]; break; }
  }
  _Float16* Pbuf = (_Float16*)take((size_t)N_NODES*CH*64*2);
  const int K = CH*64;
  const int nslots = K / 1024;   // Cpart slots per chunk (>=1); total across chunks = 8

  hipMemsetAsync(cnt, 0, N_NODES*4, stream);

  k_prep_bpack<<<(HIDW*DD/32)*4*64*8/256, 256, 0, stream>>>(h2_w, Bpack);
  k_prep_wT<<<(12288*2+32768+16384)/256, 256, 0, stream>>>(gru_w_ih, gru_w_hh, lstm_w_ih, lstm_w_hh,
                                                           WihT, WhhT, IhT, HhT);
  k_count<<<(N_EDGES+255)/256, 256, 0, stream>>>(tgtA, cnt);
  k_scan<<<1, 1024, 0, stream>>>(cnt, offs, cursor, deg);
  k_sortE<<<(N_EDGES+255)/256, 256, 0, stream>>>(tgtA, srcA, cursor, srcS, pos);
  k_graphoff<<<1, 128, 0, stream>>>(batch, goff);
  k_lin0<<<N_NODES/4, 256, 0, stream>>>(x, lin0_w, lin0_b, sbuf);
  k_hid<<<N_EDGES/2, 256, 0, stream>>>(ea, h1_w, h1_b, pos, hidS);

  auto launch_agg = [&](int c0, bool writeS){
    dim3 g(N_NODES);
    if (writeS){
      switch (CH){
        case 128: k_aggpre_t<128,true><<<g,256,0,stream>>>(sbuf,hidS,offs,srcS,c0,Pbuf,Ssum); break;
        case  64: k_aggpre_t< 64,true><<<g,256,0,stream>>>(sbuf,hidS,offs,srcS,c0,Pbuf,Ssum); break;
        case  32: k_aggpre_t< 32,true><<<g,256,0,stream>>>(sbuf,hidS,offs,srcS,c0,Pbuf,Ssum); break;
        default : k_aggpre_t< 16,true><<<g,256,0,stream>>>(sbuf,hidS,offs,srcS,c0,Pbuf,Ssum); break;
      }
    } else {
      switch (CH){
        case 128: k_aggpre_t<128,false><<<g,256,0,stream>>>(sbuf,hidS,offs,srcS,c0,Pbuf,Ssum); break;
        case  64: k_aggpre_t< 64,false><<<g,256,0,stream>>>(sbuf,hidS,offs,srcS,c0,Pbuf,Ssum); break;
        case  32: k_aggpre_t< 32,false><<<g,256,0,stream>>>(sbuf,hidS,offs,srcS,c0,Pbuf,Ssum); break;
        default : k_aggpre_t< 16,false><<<g,256,0,stream>>>(sbuf,hidS,offs,srcS,c0,Pbuf,Ssum); break;
      }
    }
  };

  for (int it = 0; it < 3; ++it){
    int nch = HIDW / CH;
    for (int c = 0; c < nch; ++c){
      int c0 = c*CH;
      launch_agg(c0, c == 0);
      k_gemm_lds<<<dim3(N_NODES/16, nslots), 256, 0, stream>>>(
          Pbuf, Bpack + (size_t)(c0*2)*(4*64*8),
          Cpart + (size_t)(c*nslots)*(N_NODES*64), K);
    }
    k_node_update<<<N_NODES/4, 256, 0, stream>>>(Cpart, Ssum, h2_b, deg, sbuf, conv_root, conv_bias,
                                                 WihT, WhhT, gru_b_ih, gru_b_hh);
  }

  for (int st = 0; st < 3; ++st){
    k_s2s_lstm<<<N_GRAPH, 256, 0, stream>>>(qstar, hsb, csb, IhT, HhT, lstm_b_ih, lstm_b_hh, st == 0);
    k_s2s_e<<<N_NODES/4, 256, 0, stream>>>(sbuf, hsb, batch, ebuf);
    k_s2s_ms<<<N_GRAPH, 256, 0, stream>>>(ebuf, goff, sinv);
    k_s2s_rp<<<dim3(N_GRAPH, 8), 256, 0, stream>>>(sbuf, ebuf, goff, rpart);
    k_s2s_rf<<<N_GRAPH, 64, 0, stream>>>(rpart, hsb, sinv, qstar);
  }
  k_final64<<<N_GRAPH, 256, 0, stream>>>(qstar, lin1_w, lin1_b, lin2_w, lin2_b, (float*)d_out);
}